// Round 1
// baseline (295.185 us; speedup 1.0000x reference)
//
#include <hip/hip_runtime.h>

// Problem: out[n,m,:] = emb[m, g, :] / max(||emb[m,g,:]||, 1e-12), g = gene_seq[n,m]
// N=256, M=2000, D=128. Output 262 MB fp32 -> write-BW bound.
// Fused on-the-fly normalization: 32 lanes per row (float4 each), width-32
// shuffle reduction for sum-of-squares. Two rows per wave64.

#define N_SEQ   256
#define M_GENES 2000
#define D_DIM   128
// float4s per n-slice: M_GENES * D_DIM / 4 = 64000
#define J_PER_N (M_GENES * D_DIM / 4)

__global__ __launch_bounds__(256) void GeneEmbedder_kernel(
    const int*   __restrict__ gene_seq,   // (N, M) int32
    const float* __restrict__ emb,        // (M, 4, D) fp32
    float*       __restrict__ out)        // (N, M, D) fp32
{
    const int n = blockIdx.y;
    const int j = blockIdx.x * 256 + threadIdx.x;      // 0 .. 63999 (float4 index in this n-slice)
    const int m = j >> 5;                              // row (gene) index: 32 float4s per row
    const int c = j & 31;                              // float4 index within the 128-float row

    const int g = gene_seq[n * M_GENES + m];           // same addr for 32 lanes -> broadcast

    // emb row base: ((m*4 + g) * 128) floats; our chunk at + c*4 floats (16B aligned)
    const float4 v = *reinterpret_cast<const float4*>(
        emb + ((((m << 2) + g) << 7) + (c << 2)));

    float ss = v.x * v.x + v.y * v.y + v.z * v.z + v.w * v.w;
    // reduce across the 32 lanes holding this row (wave64 = 2 rows; width=32 isolates them)
    ss += __shfl_xor(ss, 1, 32);
    ss += __shfl_xor(ss, 2, 32);
    ss += __shfl_xor(ss, 4, 32);
    ss += __shfl_xor(ss, 8, 32);
    ss += __shfl_xor(ss, 16, 32);

    const float inv = 1.0f / fmaxf(sqrtf(ss), 1e-12f);

    float4 o;
    o.x = v.x * inv;
    o.y = v.y * inv;
    o.z = v.z * inv;
    o.w = v.w * inv;

    *reinterpret_cast<float4*>(
        out + (size_t)n * (M_GENES * D_DIM) + ((size_t)j << 2)) = o;
}

extern "C" void kernel_launch(void* const* d_in, const int* in_sizes, int n_in,
                              void* d_out, int out_size, void* d_ws, size_t ws_size,
                              hipStream_t stream) {
    const int*   gene_seq = (const int*)d_in[0];
    const float* emb      = (const float*)d_in[1];
    float*       out      = (float*)d_out;

    dim3 grid(J_PER_N / 256, N_SEQ, 1);   // (250, 256)
    dim3 block(256, 1, 1);
    GeneEmbedder_kernel<<<grid, block, 0, stream>>>(gene_seq, emb, out);
}

// Round 3
// 270.847 us; speedup vs baseline: 1.0899x; 1.0899x over previous
//
#include <hip/hip_runtime.h>

// out[n,m,:] = emb[m, g, :] * inv_norm(m,g),  g = gene_seq[n,m]
// N=256, M=2000, D=128. Output 262 MB fp32 -> write-BW bound (~40 us floor).
//
// R1 was 295 us (~0.9 TB/s): serial chain (g-load -> gather -> 5-shuffle
// reduction -> store) with one unit of work per thread, no pipelining.
// R2/R3: phase 1 precomputes inv_norm[m*4+g] (8000 floats, 32 KB) into d_ws;
// phase 2 is a 10-iteration gather/scale/store with all g-loads hoistable
// (independent addresses) and nontemporal output stores to keep the 4 MB
// table resident in L2. R3 fixes the compile error: nontemporal builtin
// needs a native clang vector type, not HIP_vector_type<float,4>.

#define N_SEQ   256
#define M_GENES 2000
#define D_DIM   128
#define ROWS    (M_GENES * 4)                 // 8000 table rows
#define P2_BX   25                            // phase-2 grid.x
#define P2_IT   10                            // 25*256*10 == 64000 exactly

typedef float vfloat4 __attribute__((ext_vector_type(4)));

__global__ __launch_bounds__(256) void inv_norm_kernel(
    const float* __restrict__ emb,            // (M,4,D)
    float*       __restrict__ inv_norm)       // (M*4)
{
    const int idx = blockIdx.x * 256 + threadIdx.x;   // 0 .. 255999
    const int row = idx >> 5;                         // 0 .. 7999
    const int c   = idx & 31;

    const vfloat4 v = *reinterpret_cast<const vfloat4*>(emb + ((row << 7) + (c << 2)));
    float ss = v.x * v.x + v.y * v.y + v.z * v.z + v.w * v.w;
    ss += __shfl_xor(ss, 1, 32);
    ss += __shfl_xor(ss, 2, 32);
    ss += __shfl_xor(ss, 4, 32);
    ss += __shfl_xor(ss, 8, 32);
    ss += __shfl_xor(ss, 16, 32);
    const float inv = 1.0f / fmaxf(sqrtf(ss), 1e-12f);
    if (c == 0) inv_norm[row] = inv;
}

__global__ __launch_bounds__(256) void gather_scale_kernel(
    const int*   __restrict__ gene_seq,       // (N,M)
    const float* __restrict__ emb,            // (M,4,D)
    const float* __restrict__ inv_norm,       // (M*4)
    float*       __restrict__ out)            // (N,M,D)
{
    const int n = blockIdx.y;
    const int* __restrict__ gs = gene_seq + n * M_GENES;
    float* __restrict__ outn = out + (size_t)n * (M_GENES * D_DIM);

    const int j0 = blockIdx.x * 256 + threadIdx.x;

    #pragma unroll
    for (int it = 0; it < P2_IT; ++it) {
        const int j = j0 + it * (P2_BX * 256);        // < 64000, exact cover
        const int m = j >> 5;
        const int c = j & 31;

        const int   g   = gs[m];                      // independent across it -> hoistable
        const int   row = (m << 2) + g;
        const float inv = inv_norm[row];
        const vfloat4 v = *reinterpret_cast<const vfloat4*>(emb + ((row << 7) + (c << 2)));

        vfloat4 o = v * inv;
        __builtin_nontemporal_store(o, reinterpret_cast<vfloat4*>(outn + ((size_t)j << 2)));
    }
}

extern "C" void kernel_launch(void* const* d_in, const int* in_sizes, int n_in,
                              void* d_out, int out_size, void* d_ws, size_t ws_size,
                              hipStream_t stream) {
    const int*   gene_seq = (const int*)d_in[0];
    const float* emb      = (const float*)d_in[1];
    float*       out      = (float*)d_out;
    float*       inv_norm = (float*)d_ws;             // 8000 floats = 32 KB

    // Phase 1: 8000 rows, 32 lanes/row -> 256000 threads -> 1000 blocks
    inv_norm_kernel<<<dim3(ROWS * 32 / 256), dim3(256), 0, stream>>>(emb, inv_norm);

    // Phase 2: grid (25, 256), 10 float4s per thread
    gather_scale_kernel<<<dim3(P2_BX, N_SEQ), dim3(256), 0, stream>>>(
        gene_seq, emb, inv_norm, out);
}